// Round 2
// baseline (1924.701 us; speedup 1.0000x reference)
//
#include <hip/hip_runtime.h>
#include <hip/hip_fp16.h>

#define NB 64
#define TT 1024
#define FF 256
#define HH 256
#define GG 768
#define AA 8
#define KP 288          // padded K: 256 (x) + 8 (a) + 24 zeros
#define MM (NB*TT)      // 65536 rows

typedef _Float16 h2v __attribute__((ext_vector_type(2)));
typedef _Float16 v8h __attribute__((ext_vector_type(8)));
typedef float    v4f __attribute__((ext_vector_type(4)));

static __device__ __forceinline__ float fdot2f(unsigned a, unsigned b, float c) {
#if __has_builtin(__builtin_amdgcn_fdot2)
    return __builtin_amdgcn_fdot2(__builtin_bit_cast(h2v, a),
                                  __builtin_bit_cast(h2v, b), c, false);
#else
    h2v av = __builtin_bit_cast(h2v, a), bv = __builtin_bit_cast(h2v, b);
    return c + (float)av.x * (float)bv.x + (float)av.y * (float)bv.y;
#endif
}

static __device__ __forceinline__ unsigned pk_rtn(float a, float b) {
    unsigned lo = (unsigned)__half_as_ushort(__float2half(a));
    unsigned hi = (unsigned)__half_as_ushort(__float2half(b));
    return lo | (hi << 16);
}

// ---------------------------------------------------------------------------
// Kernel 0: robust reset-dtype detection + canonicalization to uint8.
// The harness may upload the bool array as int32 (4B) or byte-bool (1B).
// Under the byte-bool interpretation the array is exactly 16384 dwords; we
// read only those for detection (safe under both interpretations). int32
// 0/1 little-endian dwords have upper 3 bytes == 0; byte-bools (~50% ones)
// make the OR of upper bytes nonzero with overwhelming probability.
// One workgroup of 1024 threads.
// ---------------------------------------------------------------------------
__global__ __launch_bounds__(1024) void fix_reset(
    const unsigned* __restrict__ src, unsigned char* __restrict__ dst)
{
    __shared__ unsigned red[16];
    const int tid = threadIdx.x;

    unsigned acc = 0;
    #pragma unroll
    for (int i = 0; i < 16; i++)
        acc |= src[tid * 16 + i] & 0xFFFFFF00u;
    // wave-reduce OR
    #pragma unroll
    for (int off = 32; off >= 1; off >>= 1)
        acc |= __shfl_down(acc, off, 64);
    if ((tid & 63) == 0) red[tid >> 6] = acc;
    __syncthreads();
    unsigned flag = 0;
    #pragma unroll
    for (int i = 0; i < 16; i++) flag |= red[i];
    const bool is_i32 = (flag == 0);

    if (is_i32) {
        // 65536 int32 -> 65536 bytes
        const int per = (NB * TT) / 1024;   // 64
        #pragma unroll
        for (int i = 0; i < per; i++) {
            int idx = tid * per + i;
            dst[idx] = (unsigned char)(src[idx] != 0 ? 1 : 0);
        }
    } else {
        // already byte-bools: copy 64 KB as dwords
        unsigned* d4 = (unsigned*)dst;
        #pragma unroll
        for (int i = 0; i < 16; i++)
            d4[tid * 16 + i] = src[tid * 16 + i];
    }
}

// ---------------------------------------------------------------------------
// Kernel 1: build fp16 padded activation matrix xa[MM][KP] = [x | a | 0],
// transposed padded weights wt[GG][KP] = [w_i ; w_a ; 0]^T, and output #3.
// ---------------------------------------------------------------------------
__global__ __launch_bounds__(256) void prepass(
    const float* __restrict__ x, const float* __restrict__ a,
    const float* __restrict__ w_i, const float* __restrict__ w_a,
    const float* __restrict__ ihg, float* __restrict__ out3,
    unsigned short* __restrict__ xa, unsigned short* __restrict__ wt)
{
    int idx = blockIdx.x * 256 + threadIdx.x;
    const int E1 = MM * KP;          // 18,874,368
    const int E2 = GG * KP;          // 221,184
    if (idx < E1) {
        int m = idx / KP, k = idx - m * KP;
        float v = 0.f;
        if (k < FF)            v = x[m * FF + k];
        else if (k < FF + AA)  v = a[m * AA + (k - FF)];
        xa[idx] = __half_as_ushort(__float2half(v));
    } else if (idx < E1 + E2) {
        int j = idx - E1;
        int g = j / KP, k = j - g * KP;
        float v = 0.f;
        if (k < FF)            v = w_i[k * GG + g];
        else if (k < FF + AA)  v = w_a[(k - FF) * GG + g];
        wt[j] = __half_as_ushort(__float2half(v));
    } else if (idx < E1 + E2 + HH) {
        int i = idx - E1 - E2;
        out3[i] = ihg[i];
    }
}

// ---------------------------------------------------------------------------
// Kernel 2: gxa[MM][GG] (fp16) = xa @ W + bias, via mfma_f32_16x16x32_f16.
// 128x128 tile per block, 4 waves, each wave a 32x128 strip. K = 9 chunks of 32.
// ---------------------------------------------------------------------------
#define LDK 40   // LDS row stride in halfs (80 B): 16B-aligned, 2-way banks only

__global__ __launch_bounds__(256) void gemm_gxa(
    const unsigned short* __restrict__ xa, const unsigned short* __restrict__ wt,
    const float* __restrict__ bias, unsigned short* __restrict__ gxa)
{
    __shared__ __align__(16) unsigned short As[128 * LDK];
    __shared__ __align__(16) unsigned short Bs[128 * LDK];

    const int bid = blockIdx.x;
    const int gt = bid % 6, mt = bid / 6;
    const int tid = threadIdx.x;
    const int lane = tid & 63, wv = tid >> 6;
    const int srow = tid & 127, shf = tid >> 7;
    const int r15 = lane & 15, q = lane >> 4;

    v4f acc[2][8];
    #pragma unroll
    for (int i = 0; i < 2; i++)
        #pragma unroll
        for (int j = 0; j < 8; j++) acc[i][j] = (v4f){0.f, 0.f, 0.f, 0.f};

    for (int kc = 0; kc < 9; kc++) {
        const uint4* srcA = (const uint4*)(xa + (mt * 128 + srow) * KP + kc * 32 + shf * 16);
        const uint4* srcB = (const uint4*)(wt + (gt * 128 + srow) * KP + kc * 32 + shf * 16);
        uint4 a0 = srcA[0], a1 = srcA[1];
        uint4 b0 = srcB[0], b1 = srcB[1];
        *(uint4*)(As + srow * LDK + shf * 16)     = a0;
        *(uint4*)(As + srow * LDK + shf * 16 + 8) = a1;
        *(uint4*)(Bs + srow * LDK + shf * 16)     = b0;
        *(uint4*)(Bs + srow * LDK + shf * 16 + 8) = b1;
        __syncthreads();

        v8h af[2], bf[8];
        #pragma unroll
        for (int mi = 0; mi < 2; mi++)
            af[mi] = *(const v8h*)(As + (wv * 32 + mi * 16 + r15) * LDK + q * 8);
        #pragma unroll
        for (int nj = 0; nj < 8; nj++)
            bf[nj] = *(const v8h*)(Bs + (nj * 16 + r15) * LDK + q * 8);
        #pragma unroll
        for (int mi = 0; mi < 2; mi++)
            #pragma unroll
            for (int nj = 0; nj < 8; nj++)
                acc[mi][nj] = __builtin_amdgcn_mfma_f32_16x16x32_f16(
                    af[mi], bf[nj], acc[mi][nj], 0, 0, 0);
        __syncthreads();
    }

    #pragma unroll
    for (int mi = 0; mi < 2; mi++) {
        #pragma unroll
        for (int nj = 0; nj < 8; nj++) {
            int col = gt * 128 + nj * 16 + r15;
            float bv = bias[col];
            #pragma unroll
            for (int v = 0; v < 4; v++) {
                int row = mt * 128 + wv * 32 + mi * 16 + q * 4 + v;
                float val = acc[mi][nj][v] + bv;
                gxa[row * GG + col] = __half_as_ushort(__float2half(val));
            }
        }
    }
}

// ---------------------------------------------------------------------------
// Kernel 3: persistent GRU scan. One block (512 thr) per sequence.
// fp16 w_h lives entirely in registers (192 packed dwords/lane).
// Phase1: zr gates (512), lane = (gate-pair gi, k-half kh). Phase2: a gates
// (256), lane = (gate-pair g2i, k-quarter kq). h broadcast via LDS half2.
// ---------------------------------------------------------------------------
__global__ __launch_bounds__(512) void scan_kernel(
    const unsigned short* __restrict__ gxa, const float* __restrict__ w_h,
    const unsigned char* __restrict__ reset, const float* __restrict__ ihg,
    float* __restrict__ out)
{
    __shared__ __align__(16) unsigned int h_pk[128];   // h as packed half2
    __shared__ __align__(16) unsigned int rh_pk[128];  // r*h as packed half2
    __shared__ float2 part_zr[256];
    __shared__ float2 part_a[3][128];
    __shared__ __align__(4) unsigned char rst[TT];

    const int n   = blockIdx.x;
    const int tid = threadIdx.x;
    const int kh  = tid >> 8, gi  = tid & 255;   // phase1 role
    const int kq  = tid >> 7, g2i = tid & 127;   // phase2 role

    // stage canonical uint8 reset flags for this sequence
    if (tid < 256)
        ((unsigned int*)rst)[tid] = ((const unsigned int*)(reset + n * TT))[tid];

    // ---- load recurrent weights into registers (fp16 packed pairs) ----
    unsigned wz0[64], wz1[64];   // phase1: gates 2*gi, 2*gi+1; k in [kh*128, +128)
    {
        const int gA = 2 * gi;
        #pragma unroll
        for (int i = 0; i < 64; i++) {
            int k = kh * 128 + 2 * i;
            wz0[i] = pk_rtn(w_h[k * GG + gA],     w_h[(k + 1) * GG + gA]);
            wz1[i] = pk_rtn(w_h[k * GG + gA + 1], w_h[(k + 1) * GG + gA + 1]);
        }
    }
    unsigned wa0[32], wa1[32];   // phase2: gates 512+2*g2i, +1; k in [kq*64, +64)
    {
        const int gB = 512 + 2 * g2i;
        #pragma unroll
        for (int i = 0; i < 32; i++) {
            int k = kq * 64 + 2 * i;
            wa0[i] = pk_rtn(w_h[k * GG + gB],     w_h[(k + 1) * GG + gB]);
            wa1[i] = pk_rtn(w_h[k * GG + gB + 1], w_h[(k + 1) * GG + gB + 1]);
        }
    }

    // ---- hidden state: lane tid<128 owns h[2*tid], h[2*tid+1] in fp32 ----
    float ih0 = 0.f, ih1 = 0.f, hp0 = 0.f, hp1 = 0.f;
    if (tid < 128) {
        ih0 = ihg[2 * tid]; ih1 = ihg[2 * tid + 1];
        hp0 = ih0; hp1 = ih1;
    }
    __syncthreads();  // rst staged

    const unsigned* gxau = (const unsigned*)gxa;
    int m0 = n * TT;
    unsigned gzr = gxau[m0 * 384 + (tid & 255)];
    unsigned gaa = gxau[m0 * 384 + 256 + (tid & 127)];

    float zA = 0.f, zB = 0.f, hc0 = 0.f, hc1 = 0.f;

    for (int t = 0; t < TT; t++) {
        // apply reset, publish h (packed fp16) for broadcast
        if (tid < 128) {
            bool rb = rst[t] != 0;
            hc0 = rb ? ih0 : hp0;
            hc1 = rb ? ih1 : hp1;
            h_pk[tid] = __builtin_bit_cast(unsigned,
                          __builtin_amdgcn_cvt_pkrtz(hc0, hc1));
        }
        __syncthreads();  // B1

        // prefetch next step's gxa
        int mn = m0 + (t + 1 < TT ? t + 1 : t);
        unsigned gzr_n = gxau[mn * 384 + (tid & 255)];
        unsigned gaa_n = gxau[mn * 384 + 256 + (tid & 127)];

        // ---- phase 1: zr partial dots (this lane: 2 gates, 128 k) ----
        float a00 = 0.f, a01 = 0.f, a10 = 0.f, a11 = 0.f;
        const uint4* h4 = (const uint4*)h_pk;
        #pragma unroll
        for (int c = 0; c < 16; c++) {
            uint4 qd = h4[kh * 16 + c];
            a00 = fdot2f(qd.x, wz0[4*c+0], a00);
            a01 = fdot2f(qd.y, wz0[4*c+1], a01);
            a00 = fdot2f(qd.z, wz0[4*c+2], a00);
            a01 = fdot2f(qd.w, wz0[4*c+3], a01);
            a10 = fdot2f(qd.x, wz1[4*c+0], a10);
            a11 = fdot2f(qd.y, wz1[4*c+1], a11);
            a10 = fdot2f(qd.z, wz1[4*c+2], a10);
            a11 = fdot2f(qd.w, wz1[4*c+3], a11);
        }
        float pA = a00 + a01, pB = a10 + a11;
        if (kh) part_zr[gi] = make_float2(pA, pB);
        __syncthreads();  // B2

        if (tid < 256) {  // kh==0 lanes combine + activate
            float2 o = part_zr[gi];
            h2v gz = __builtin_bit_cast(h2v, gzr);
            float vA = pA + o.x + (float)gz.x;
            float vB = pB + o.y + (float)gz.y;
            float sA = 1.f / (1.f + __expf(-vA));
            float sB = 1.f / (1.f + __expf(-vB));
            if (gi < 128) { zA = sA; zB = sB; }          // z pair (gates 2gi,2gi+1)
            else {                                        // r pair -> r*h
                int j2 = gi - 128;
                h2v hp = __builtin_bit_cast(h2v, h_pk[j2]);
                float r0 = sA * (float)hp.x, r1 = sB * (float)hp.y;
                rh_pk[j2] = __builtin_bit_cast(unsigned,
                              __builtin_amdgcn_cvt_pkrtz(r0, r1));
            }
        }
        __syncthreads();  // B3

        // ---- phase 2: a-gate partial dots (this lane: 2 gates, 64 k) ----
        float c00 = 0.f, c01 = 0.f, c10 = 0.f, c11 = 0.f;
        const uint4* r4 = (const uint4*)rh_pk;
        #pragma unroll
        for (int c = 0; c < 8; c++) {
            uint4 qd = r4[kq * 8 + c];
            c00 = fdot2f(qd.x, wa0[4*c+0], c00);
            c01 = fdot2f(qd.y, wa0[4*c+1], c01);
            c00 = fdot2f(qd.z, wa0[4*c+2], c00);
            c01 = fdot2f(qd.w, wa0[4*c+3], c01);
            c10 = fdot2f(qd.x, wa1[4*c+0], c10);
            c11 = fdot2f(qd.y, wa1[4*c+1], c11);
            c10 = fdot2f(qd.z, wa1[4*c+2], c10);
            c11 = fdot2f(qd.w, wa1[4*c+3], c11);
        }
        float qA = c00 + c01, qB = c10 + c11;
        if (kq) part_a[kq - 1][g2i] = make_float2(qA, qB);
        __syncthreads();  // B4

        if (tid < 128) {  // combine, tanh, state update, store
            float2 p0 = part_a[0][tid], p1 = part_a[1][tid], p2 = part_a[2][tid];
            h2v ga = __builtin_bit_cast(h2v, gaa);
            float uA = qA + p0.x + p1.x + p2.x + (float)ga.x;
            float uB = qB + p0.y + p1.y + p2.y + (float)ga.y;
            float e2A = __expf(2.f * uA), e2B = __expf(2.f * uB);
            float tA = (e2A - 1.f) / (e2A + 1.f);
            float tB = (e2B - 1.f) / (e2B + 1.f);
            float hn0 = hc0 + zA * (tA - hc0);
            float hn1 = hc1 + zB * (tB - hc1);
            int o = (m0 + t) * HH + 2 * tid;
            *(float2*)(out + o) = make_float2(hn0, hn1);                 // outputs
            *(float2*)(out + MM * HH + o) = make_float2(hn0, hn1);       // states
            hp0 = hn0; hp1 = hn1;
        }
        gzr = gzr_n; gaa = gaa_n;
    }
}

// ---------------------------------------------------------------------------
extern "C" void kernel_launch(void* const* d_in, const int* in_sizes, int n_in,
                              void* d_out, int out_size, void* d_ws, size_t ws_size,
                              hipStream_t stream)
{
    const float* x   = (const float*)d_in[0];
    const float* a   = (const float*)d_in[1];
    const void*  rsv = d_in[2];
    const float* w_i = (const float*)d_in[3];
    const float* w_h = (const float*)d_in[4];
    const float* w_a = (const float*)d_in[5];
    const float* b   = (const float*)d_in[6];
    const float* ih  = (const float*)d_in[7];
    float*       out = (float*)d_out;

    char* ws = (char*)d_ws;
    unsigned short* gxa  = (unsigned short*)ws;                                  // MM*GG fp16 (96 MB)
    unsigned short* xa   = (unsigned short*)(ws + (size_t)MM * GG * 2);          // MM*KP fp16 (37.7 MB)
    unsigned short* wt   = (unsigned short*)(ws + (size_t)MM * GG * 2
                                                + (size_t)MM * KP * 2);          // GG*KP fp16 (0.44 MB)
    unsigned char*  rst8 = (unsigned char*)(ws + (size_t)MM * GG * 2
                                               + (size_t)MM * KP * 2
                                               + (size_t)GG * KP * 2);           // 64 KB canonical resets

    fix_reset<<<1, 1024, 0, stream>>>((const unsigned*)rsv, rst8);

    int total = MM * KP + GG * KP + HH;
    int pblocks = (total + 255) / 256;
    prepass<<<pblocks, 256, 0, stream>>>(x, a, w_i, w_a, ih,
                                         out + (size_t)2 * MM * HH, xa, wt);
    gemm_gxa<<<512 * 6, 256, 0, stream>>>(xa, wt, b, gxa);
    scan_kernel<<<NB, 512, 0, stream>>>(gxa, w_h, rst8, ih, out);
}